// Round 3
// baseline (6332.660 us; speedup 1.0000x reference)
//
#include <hip/hip_runtime.h>
#include <hip/hip_bf16.h>
#include <hip/hip_fp8.h>

#define V  32000
#define D  512
#define H  512
#define B  32
#define T  128
#define L  48
#define KLIN 1024
#define KGRU 1536
#define RESCUE_DELTA 0.16f

typedef __attribute__((ext_vector_type(8))) short bf16x8;
typedef __attribute__((ext_vector_type(4))) float f32x4;

// ---------- f32 -> (bf16 hi, bf16 lo) split, RNE ----------
__device__ __forceinline__ void split1(float f, unsigned short* hi, unsigned short* lo) {
    unsigned u  = __float_as_uint(f);
    unsigned uh = u + (0x7FFFu + ((u >> 16) & 1u));
    unsigned short hs = (unsigned short)(uh >> 16);
    float hf = __uint_as_float(((unsigned)hs) << 16);
    float l  = f - hf;
    unsigned ul = __float_as_uint(l);
    ul += 0x7FFFu + ((ul >> 16) & 1u);
    *hi = hs;
    *lo = (unsigned short)(ul >> 16);
}

__device__ __forceinline__ void split8(const float* __restrict__ p, bf16x8& hi, bf16x8& lo) {
    float4 w0 = reinterpret_cast<const float4*>(p)[0];
    float4 w1 = reinterpret_cast<const float4*>(p)[1];
    float w[8] = {w0.x, w0.y, w0.z, w0.w, w1.x, w1.y, w1.z, w1.w};
    #pragma unroll
    for (int i = 0; i < 8; ++i) {
        unsigned u  = __float_as_uint(w[i]);
        unsigned uh = u + (0x7FFFu + ((u >> 16) & 1u));
        unsigned short hs = (unsigned short)(uh >> 16);
        float hf = __uint_as_float(((unsigned)hs) << 16);
        float l  = w[i] - hf;
        unsigned ul = __float_as_uint(l);
        ul += 0x7FFFu + ((ul >> 16) & 1u);
        hi[i] = (short)hs;
        lo[i] = (short)(ul >> 16);
    }
}

__device__ __forceinline__ unsigned char to_fp8(float v) {
    __hip_fp8_e4m3 q(v);
    return (unsigned char)q.__x;
}

// top-2 merge: (m1,i1,m2,i2) <- merge with (om1,oi1,om2,oi2)
__device__ __forceinline__ void merge2(float& m1, int& i1, float& m2, int& i2,
                                       float om1, int oi1, float om2, int oi2) {
    bool ogt = (om1 > m1) || (om1 == m1 && oi1 < i1);
    float t1 = ogt ? om1 : m1; int ti1 = ogt ? oi1 : i1;
    float l1 = ogt ? m1 : om1; int li1 = ogt ? i1 : oi1;   // loser of top fight
    float w2 = ogt ? om2 : m2; int wi2 = ogt ? oi2 : i2;   // winner's second
    bool lgt = (l1 > w2) || (l1 == w2 && li1 < wi2);
    m1 = t1; i1 = ti1;
    m2 = lgt ? l1 : w2; i2 = lgt ? li1 : wi2;
}

// ---------- one-time: linW -> fp8 (x1024), wave-coalesced tile layout ----------
// addr(col,k) = (col>>4)*16384 + (k>>5)*512 + ((k>>3)&3)*128 + (col&15)*8 + (k&7)
__global__ void presplit_lin8(const float* __restrict__ src, unsigned char* __restrict__ W8)
{
    long i = (long)blockIdx.x * 256 + threadIdx.x;   // (col, k8): col=i>>7, k=(i&127)*8
    if (i >= (long)V * 128) return;
    int col = (int)(i >> 7), k = (int)(i & 127) << 3;
    const float* p = src + (size_t)col * 1024 + k;
    float4 w0 = reinterpret_cast<const float4*>(p)[0];
    float4 w1 = reinterpret_cast<const float4*>(p)[1];
    float w[8] = {w0.x, w0.y, w0.z, w0.w, w1.x, w1.y, w1.z, w1.w};
    unsigned long long pk = 0;
    #pragma unroll
    for (int j = 0; j < 8; ++j)
        pk |= ((unsigned long long)to_fp8(w[j] * 1024.f)) << (8 * j);
    size_t addr = (size_t)(col >> 4) * 16384 + (size_t)(k >> 5) * 512
                + (size_t)((k >> 3) & 3) * 128 + (size_t)(col & 15) * 8;
    *(unsigned long long*)(W8 + addr) = pk;
}

// ---------- one-time: split gru weights into combined [1536][1536] K-layout ----------
__global__ void presplit_gru(const float* __restrict__ Wih, const float* __restrict__ Whh,
                             unsigned short* __restrict__ hi, unsigned short* __restrict__ lo)
{
    int i = blockIdx.x * 256 + threadIdx.x;
    if (i >= 1536 * 192) return;
    int col = i / 192, k = (i % 192) * 8;
    const float* src = (k < 1024) ? (Wih + (size_t)col * 1024 + k)
                                  : (Whh + (size_t)col * 512 + (k - 1024));
    bf16x8 h8, l8;
    split8(src, h8, l8);
    *(bf16x8*)(hi + (size_t)col * KGRU + k) = h8;
    *(bf16x8*)(lo + (size_t)col * KGRU + k) = l8;
}

// ---------- init ----------
__global__ void init_state(const int* __restrict__ inputs, const float* __restrict__ context,
                           const float* __restrict__ emb, float* __restrict__ h_t,
                           unsigned short* __restrict__ Xghi, unsigned short* __restrict__ Xglo,
                           unsigned char* __restrict__ X8, float* __restrict__ Xf)
{
    int idx = blockIdx.x * 256 + threadIdx.x;   // 0..B*H-1
    int b = idx >> 9, j = idx & 511;
    int tok = inputs[b];
    float e = emb[(size_t)tok * D + j];
    split1(e, &Xghi[b * KGRU + j], &Xglo[b * KGRU + j]);
    float c = context[b * H + j];
    split1(c, &Xghi[b * KGRU + 512 + j], &Xglo[b * KGRU + 512 + j]);
    Xghi[b * KGRU + 1024 + j] = 0;
    Xglo[b * KGRU + 1024 + j] = 0;
    X8[b * 1024 + 512 + j] = to_fp8(c * 64.f);
    Xf[b * 1024 + 512 + j] = c;
    h_t[j * 32 + b] = 0.f;
}

// ---------- energies = enc @ attn_W^T + attn_b (once) ----------
__global__ void __launch_bounds__(256) energies_gemm(
    const float* __restrict__ enc, const float* __restrict__ attnW,
    const float* __restrict__ attnb, float* __restrict__ energies)
{
    int wave = threadIdx.x >> 6, lane = threadIdx.x & 63;
    int col = blockIdx.y * 64 + wave * 16 + (lane & 15);
    int kg  = (lane >> 4) * 8;
    int arow0 = blockIdx.x * 32 + (lane & 15);
    f32x4 acc0 = {0.f,0.f,0.f,0.f}, acc1 = {0.f,0.f,0.f,0.f};
    for (int k0 = 0; k0 < 512; k0 += 32) {
        bf16x8 bh, bl;  split8(attnW + (size_t)col * 512 + k0 + kg, bh, bl);
        bf16x8 a0h, a0l; split8(enc + (size_t)arow0 * 512 + k0 + kg, a0h, a0l);
        bf16x8 a1h, a1l; split8(enc + (size_t)(arow0 + 16) * 512 + k0 + kg, a1h, a1l);
        acc0 = __builtin_amdgcn_mfma_f32_16x16x32_bf16(a0h, bh, acc0, 0, 0, 0);
        acc1 = __builtin_amdgcn_mfma_f32_16x16x32_bf16(a1h, bh, acc1, 0, 0, 0);
        acc0 = __builtin_amdgcn_mfma_f32_16x16x32_bf16(a0l, bh, acc0, 0, 0, 0);
        acc1 = __builtin_amdgcn_mfma_f32_16x16x32_bf16(a1l, bh, acc1, 0, 0, 0);
        acc0 = __builtin_amdgcn_mfma_f32_16x16x32_bf16(a0h, bl, acc0, 0, 0, 0);
        acc1 = __builtin_amdgcn_mfma_f32_16x16x32_bf16(a1h, bl, acc1, 0, 0, 0);
    }
    float bias = attnb[col];
    int r0 = (lane >> 4) * 4;
    #pragma unroll
    for (int i = 0; i < 4; ++i) {
        int row = blockIdx.x * 32 + r0 + i;
        energies[(size_t)row * 512 + col]        = acc0[i] + bias;
        energies[(size_t)(row + 16) * 512 + col] = acc1[i] + bias;
    }
}

// ---------- fused GRU ----------
__global__ void __launch_bounds__(384) gru_fused(
    const unsigned short* __restrict__ Ghi, const unsigned short* __restrict__ Glo,
    const unsigned short* __restrict__ Xghi_r, const unsigned short* __restrict__ Xglo_r,
    unsigned short* __restrict__ Xghi_w, unsigned short* __restrict__ Xglo_w,
    unsigned char* __restrict__ X8_w, float* __restrict__ Xf_w,
    const float* __restrict__ bih, const float* __restrict__ bhh,
    float* __restrict__ h_t)
{
    __shared__ float AI[3][32][16], AH[3][32][16];
    __shared__ float R[32][16], Z[32][16];
    int w = threadIdx.x >> 6, lane = threadIdx.x & 63;
    int g = (w < 3) ? w : w - 3;
    int half = (w >= 3) ? 1 : 0;
    int c = lane & 15, grp = lane >> 4, kg = grp * 8;
    int j = blockIdx.x * 16 + c;
    int gcol = g * 512 + j;
    const unsigned short* wh = Ghi + (size_t)gcol * KGRU;
    const unsigned short* wl = Glo + (size_t)gcol * KGRU;
    const unsigned short* xh = Xghi_r + (size_t)c * KGRU;
    const unsigned short* xl = Xglo_r + (size_t)c * KGRU;
    f32x4 aI0 = {0.f,0.f,0.f,0.f}, aI1 = {0.f,0.f,0.f,0.f};
    f32x4 aH0 = {0.f,0.f,0.f,0.f}, aH1 = {0.f,0.f,0.f,0.f};
    for (int k0 = half * 512; k0 < half * 512 + 512; k0 += 32) {
        bf16x8 bh = *(const bf16x8*)(wh + k0 + kg);
        bf16x8 bl = *(const bf16x8*)(wl + k0 + kg);
        bf16x8 a0h = *(const bf16x8*)(xh + k0 + kg);
        bf16x8 a0l = *(const bf16x8*)(xl + k0 + kg);
        bf16x8 a1h = *(const bf16x8*)(xh + 16 * KGRU + k0 + kg);
        bf16x8 a1l = *(const bf16x8*)(xl + 16 * KGRU + k0 + kg);
        aI0 = __builtin_amdgcn_mfma_f32_16x16x32_bf16(a0h, bh, aI0, 0, 0, 0);
        aI1 = __builtin_amdgcn_mfma_f32_16x16x32_bf16(a1h, bh, aI1, 0, 0, 0);
        aI0 = __builtin_amdgcn_mfma_f32_16x16x32_bf16(a0l, bh, aI0, 0, 0, 0);
        aI1 = __builtin_amdgcn_mfma_f32_16x16x32_bf16(a1l, bh, aI1, 0, 0, 0);
        aI0 = __builtin_amdgcn_mfma_f32_16x16x32_bf16(a0h, bl, aI0, 0, 0, 0);
        aI1 = __builtin_amdgcn_mfma_f32_16x16x32_bf16(a1h, bl, aI1, 0, 0, 0);
    }
    for (int k0 = 1024 + half * 256; k0 < 1024 + half * 256 + 256; k0 += 32) {
        bf16x8 bh = *(const bf16x8*)(wh + k0 + kg);
        bf16x8 bl = *(const bf16x8*)(wl + k0 + kg);
        bf16x8 a0h = *(const bf16x8*)(xh + k0 + kg);
        bf16x8 a0l = *(const bf16x8*)(xl + k0 + kg);
        bf16x8 a1h = *(const bf16x8*)(xh + 16 * KGRU + k0 + kg);
        bf16x8 a1l = *(const bf16x8*)(xl + 16 * KGRU + k0 + kg);
        aH0 = __builtin_amdgcn_mfma_f32_16x16x32_bf16(a0h, bh, aH0, 0, 0, 0);
        aH1 = __builtin_amdgcn_mfma_f32_16x16x32_bf16(a1h, bh, aH1, 0, 0, 0);
        aH0 = __builtin_amdgcn_mfma_f32_16x16x32_bf16(a0l, bh, aH0, 0, 0, 0);
        aH1 = __builtin_amdgcn_mfma_f32_16x16x32_bf16(a1l, bh, aH1, 0, 0, 0);
        aH0 = __builtin_amdgcn_mfma_f32_16x16x32_bf16(a0h, bl, aH0, 0, 0, 0);
        aH1 = __builtin_amdgcn_mfma_f32_16x16x32_bf16(a1h, bl, aH1, 0, 0, 0);
    }
    if (w >= 3) {
        #pragma unroll
        for (int i = 0; i < 4; ++i) {
            AI[g][grp * 4 + i][c] = aI0[i];  AI[g][grp * 4 + i + 16][c] = aI1[i];
            AH[g][grp * 4 + i][c] = aH0[i];  AH[g][grp * 4 + i + 16][c] = aH1[i];
        }
    }
    __syncthreads();
    float gi[8], gh[8];
    if (w < 3) {
        float bi = bih[gcol], bhv = bhh[gcol];
        #pragma unroll
        for (int i = 0; i < 4; ++i) {
            gi[i]     = aI0[i] + AI[g][grp * 4 + i][c]      + bi;
            gi[i + 4] = aI1[i] + AI[g][grp * 4 + i + 16][c] + bi;
            gh[i]     = aH0[i] + AH[g][grp * 4 + i][c]      + bhv;
            gh[i + 4] = aH1[i] + AH[g][grp * 4 + i + 16][c] + bhv;
        }
        if (w == 0) {
            #pragma unroll
            for (int i = 0; i < 8; ++i) {
                int b = (i < 4) ? grp * 4 + i : grp * 4 + (i - 4) + 16;
                R[b][c] = 1.f / (1.f + expf(-(gi[i] + gh[i])));
            }
        } else if (w == 1) {
            #pragma unroll
            for (int i = 0; i < 8; ++i) {
                int b = (i < 4) ? grp * 4 + i : grp * 4 + (i - 4) + 16;
                Z[b][c] = 1.f / (1.f + expf(-(gi[i] + gh[i])));
            }
        }
    }
    __syncthreads();
    if (w == 2) {
        float4 h0 = *(const float4*)(h_t + (size_t)j * 32 + grp * 4);
        float4 h1 = *(const float4*)(h_t + (size_t)j * 32 + grp * 4 + 16);
        float hold[8] = {h0.x, h0.y, h0.z, h0.w, h1.x, h1.y, h1.z, h1.w};
        float hn[8];
        #pragma unroll
        for (int i = 0; i < 8; ++i) {
            int b = (i < 4) ? grp * 4 + i : grp * 4 + (i - 4) + 16;
            float n = tanhf(gi[i] + R[b][c] * gh[i]);
            float z = Z[b][c];
            hn[i] = (1.f - z) * n + z * hold[i];
        }
        *(float4*)(h_t + (size_t)j * 32 + grp * 4)      = make_float4(hn[0], hn[1], hn[2], hn[3]);
        *(float4*)(h_t + (size_t)j * 32 + grp * 4 + 16) = make_float4(hn[4], hn[5], hn[6], hn[7]);
        #pragma unroll
        for (int i = 0; i < 8; ++i) {
            int b = (i < 4) ? grp * 4 + i : grp * 4 + (i - 4) + 16;
            X8_w[(size_t)b * 1024 + j] = to_fp8(hn[i] * 64.f);
            Xf_w[(size_t)b * 1024 + j] = hn[i];
            split1(hn[i], &Xghi_w[(size_t)b * KGRU + 1024 + j], &Xglo_w[(size_t)b * KGRU + 1024 + j]);
        }
    }
}

// ---------- score (fp8, blocks 0..499) + attention/ctx (blocks 500..531) ----------
__global__ void __launch_bounds__(256) score_attn(
    const unsigned char* __restrict__ W8, const float* __restrict__ linb,
    const unsigned char* __restrict__ X8_r,
    unsigned char* __restrict__ X8_w, float* __restrict__ Xf_w,
    unsigned short* __restrict__ Xghi_w, unsigned short* __restrict__ Xglo_w,
    const float* __restrict__ h_t, const float* __restrict__ energies,
    const float* __restrict__ enc,
    float* __restrict__ out,
    float* __restrict__ Pm, int* __restrict__ Pa,
    float* __restrict__ Pm2, int* __restrict__ Pa2,
    float* __restrict__ Ps, int t)
{
    __shared__ float Lm1[4][32], Lm2[4][32], Ls[4][32];
    __shared__ int   Li1[4][32], Li2[4][32];
    __shared__ float hrow[512], aw[128], red[256];
    int tid = threadIdx.x;
    if (blockIdx.x < 500) {
        int wave = tid >> 6, lane = tid & 63;
        int c = lane & 15, grp = lane >> 4;
        int col = blockIdx.x * 64 + wave * 16 + c;
        const unsigned char* wp = W8 + (size_t)(blockIdx.x * 4 + wave) * 16384 + grp * 128 + c * 8;
        const unsigned char* x0 = X8_r + (size_t)c * 1024 + grp * 8;
        const unsigned char* x1 = x0 + 16 * 1024;
        f32x4 acc0 = {0.f,0.f,0.f,0.f}, acc1 = {0.f,0.f,0.f,0.f};
        #pragma unroll 4
        for (int kb = 0; kb < 32; ++kb) {
            long wb = *(const long*)(wp + kb * 512);
            long a0 = *(const long*)(x0 + kb * 32);
            long a1 = *(const long*)(x1 + kb * 32);
            acc0 = __builtin_amdgcn_mfma_f32_16x16x32_fp8_fp8(a0, wb, acc0, 0, 0, 0);
            acc1 = __builtin_amdgcn_mfma_f32_16x16x32_fp8_fp8(a1, wb, acc1, 0, 0, 0);
        }
        float bias = linb[col];
        float v[8];
        int r0 = grp * 4;
        #pragma unroll
        for (int i = 0; i < 4; ++i) {
            v[i]     = acc0[i] * (1.f / 65536.f) + bias;
            v[i + 4] = acc1[i] * (1.f / 65536.f) + bias;
            out[(size_t)((r0 + i) * L + t) * V + col]      = v[i];
            out[(size_t)((r0 + i + 16) * L + t) * V + col] = v[i + 4];
        }
        // per-row top-2 + sumexp across this block's 64 cols
        #pragma unroll
        for (int i = 0; i < 8; ++i) {
            float m1 = v[i]; int i1 = col; float m2 = -INFINITY; int i2 = 0x7fffffff;
            #pragma unroll
            for (int d = 1; d < 16; d <<= 1) {
                float om1 = __shfl_xor(m1, d); int oi1 = __shfl_xor(i1, d);
                float om2 = __shfl_xor(m2, d); int oi2 = __shfl_xor(i2, d);
                merge2(m1, i1, m2, i2, om1, oi1, om2, oi2);
            }
            float s = expf(v[i] - m1);
            #pragma unroll
            for (int d = 1; d < 16; d <<= 1) s += __shfl_xor(s, d);
            if (c == 0) {
                int row = (i < 4) ? r0 + i : r0 + (i - 4) + 16;
                Lm1[wave][row] = m1; Li1[wave][row] = i1;
                Lm2[wave][row] = m2; Li2[wave][row] = i2;
                Ls[wave][row] = s;
            }
        }
        __syncthreads();
        if (tid < 32) {
            float m1 = Lm1[0][tid]; int i1 = Li1[0][tid];
            float m2 = Lm2[0][tid]; int i2 = Li2[0][tid];
            #pragma unroll
            for (int q = 1; q < 4; ++q)
                merge2(m1, i1, m2, i2, Lm1[q][tid], Li1[q][tid], Lm2[q][tid], Li2[q][tid]);
            float S = 0.f;
            #pragma unroll
            for (int q = 0; q < 4; ++q) S += Ls[q][tid] * expf(Lm1[q][tid] - m1);
            Pm [tid * 500 + blockIdx.x] = m1;
            Pa [tid * 500 + blockIdx.x] = i1;
            Pm2[tid * 500 + blockIdx.x] = m2;
            Pa2[tid * 500 + blockIdx.x] = i2;
            Ps [tid * 500 + blockIdx.x] = S;
        }
    } else {
        int b = blockIdx.x - 500;
        for (int j = tid; j < 512; j += 256) hrow[j] = h_t[(size_t)j * 32 + b];
        __syncthreads();
        {
            int tt = tid >> 1, half = tid & 1;
            const float4* e4 = (const float4*)(energies + ((size_t)(b * T + tt)) * 512 + half * 256);
            const float4* h4 = (const float4*)(hrow + half * 256);
            float p = 0.f;
            #pragma unroll 4
            for (int k = 0; k < 64; ++k) {
                float4 a = e4[k], cc = h4[k];
                p += a.x * cc.x + a.y * cc.y + a.z * cc.z + a.w * cc.w;
            }
            p += __shfl_xor(p, 1);
            if (half == 0) aw[tt] = p;
        }
        __syncthreads();
        red[tid] = (tid < 128) ? aw[tid] : -INFINITY; __syncthreads();
        for (int s = 128; s > 0; s >>= 1) { if (tid < s) red[tid] = fmaxf(red[tid], red[tid + s]); __syncthreads(); }
        float am = red[0];
        __syncthreads();
        if (tid < 128) { float e = expf(aw[tid] - am); aw[tid] = e; red[tid] = e; } else red[tid] = 0.f;
        __syncthreads();
        for (int s = 128; s > 0; s >>= 1) { if (tid < s) red[tid] += red[tid + s]; __syncthreads(); }
        float asum = red[0];
        __syncthreads();
        float c0 = 0.f, c1 = 0.f;
        for (int tt2 = 0; tt2 < T; ++tt2) {
            float a = aw[tt2];
            const float* er = enc + ((size_t)(b * T + tt2)) * 512;
            c0 += a * er[tid];
            c1 += a * er[tid + 256];
        }
        c0 /= asum; c1 /= asum;
        X8_w[(size_t)b * 1024 + 512 + tid]       = to_fp8(c0 * 64.f);
        X8_w[(size_t)b * 1024 + 512 + tid + 256] = to_fp8(c1 * 64.f);
        Xf_w[(size_t)b * 1024 + 512 + tid]       = c0;
        Xf_w[(size_t)b * 1024 + 512 + tid + 256] = c1;
        split1(c0, &Xghi_w[(size_t)b * KGRU + 512 + tid],       &Xglo_w[(size_t)b * KGRU + 512 + tid]);
        split1(c1, &Xghi_w[(size_t)b * KGRU + 512 + tid + 256], &Xglo_w[(size_t)b * KGRU + 512 + tid + 256]);
    }
}

// ---------- finalize: lse + exact-rescue argmax + emb gather ----------
__global__ void __launch_bounds__(256) finalize(
    const float* __restrict__ Pm, const int* __restrict__ Pa,
    const float* __restrict__ Pm2, const int* __restrict__ Pa2,
    const float* __restrict__ Ps,
    const float* __restrict__ linW, const float* __restrict__ linb,
    const float* __restrict__ Xf_r, const float* __restrict__ emb,
    unsigned short* __restrict__ Xghi_w, unsigned short* __restrict__ Xglo_w,
    float* __restrict__ lse_buf, int t)
{
    __shared__ float xb[1024];
    __shared__ float sred[256];
    __shared__ int   sidx[256];
    __shared__ int   list[256];
    __shared__ float cscore[256];
    __shared__ int   ncand_sh;
    int b = blockIdx.x, tid = threadIdx.x;
    for (int j = tid; j < 1024; j += 256) xb[j] = Xf_r[(size_t)b * 1024 + j];
    if (tid == 0) ncand_sh = 0;
    // pass 1: approx global max
    float m = -INFINITY;
    for (int i = tid; i < 500; i += 256) m = fmaxf(m, Pm[b * 500 + i]);
    sred[tid] = m; __syncthreads();
    for (int s = 128; s > 0; s >>= 1) { if (tid < s) sred[tid] = fmaxf(sred[tid], sred[tid + s]); __syncthreads(); }
    float M = sred[0];
    float thresh = M - RESCUE_DELTA;
    __syncthreads();
    // pass 2: sumexp + candidate collection
    float S = 0.f;
    for (int i = tid; i < 500; i += 256) {
        float pm = Pm[b * 500 + i];
        S += Ps[b * 500 + i] * expf(pm - M);
        if (pm >= thresh) {
            int p = atomicAdd(&ncand_sh, 1);
            if (p < 256) list[p] = Pa[b * 500 + i];
        }
        if (Pm2[b * 500 + i] >= thresh) {
            int p = atomicAdd(&ncand_sh, 64);   // block has >=2 near-max: rescue whole block
            for (int q = 0; q < 64; ++q) if (p + q < 256) list[p + q] = i * 64 + q;
        }
    }
    sred[tid] = S; __syncthreads();
    for (int s = 128; s > 0; s >>= 1) { if (tid < s) sred[tid] += sred[tid + s]; __syncthreads(); }
    if (tid == 0) lse_buf[b * L + t] = M + logf(sred[0]);
    __syncthreads();
    int nc = ncand_sh < 256 ? ncand_sh : 256;
    // exact f32 dots for candidates
    int wv = tid >> 6, lane = tid & 63;
    for (int ci = wv; ci < nc; ci += 4) {
        int col = list[ci];
        const float* wr = linW + (size_t)col * 1024 + lane * 16;
        const float* xr = xb + lane * 16;
        float s = 0.f;
        #pragma unroll
        for (int j = 0; j < 16; j += 4) {
            float4 a = *(const float4*)(wr + j);
            s += a.x * xr[j] + a.y * xr[j + 1] + a.z * xr[j + 2] + a.w * xr[j + 3];
        }
        #pragma unroll
        for (int d = 1; d < 64; d <<= 1) s += __shfl_xor(s, d);
        if (lane == 0) cscore[ci] = s + linb[col];
    }
    __syncthreads();
    // argmax over candidates (exact scores, lowest index on tie)
    float bm = -INFINITY; int bi = 0x7fffffff;
    for (int ci = tid; ci < nc; ci += 256) {
        float vv = cscore[ci]; int cc = list[ci];
        if (vv > bm || (vv == bm && cc < bi)) { bm = vv; bi = cc; }
    }
    sred[tid] = bm; sidx[tid] = bi; __syncthreads();
    for (int s = 128; s > 0; s >>= 1) {
        if (tid < s) {
            float ov = sred[tid + s]; int oi = sidx[tid + s];
            if (ov > sred[tid] || (ov == sred[tid] && oi < sidx[tid])) { sred[tid] = ov; sidx[tid] = oi; }
        }
        __syncthreads();
    }
    int amax = sidx[0];
    for (int j = tid; j < 512; j += 256)
        split1(emb[(size_t)amax * D + j], &Xghi_w[(size_t)b * KGRU + j], &Xglo_w[(size_t)b * KGRU + j]);
}

// ---------- final: out -= lse ----------
__global__ void __launch_bounds__(256) subtract_lse(float* __restrict__ out,
                                                    const float* __restrict__ lse_buf)
{
    long i4 = (long)blockIdx.x * 256 + threadIdx.x;
    int row = (int)(i4 / 8000);
    float l = lse_buf[row];
    float4* p = (float4*)out + i4;
    float4 v = *p;
    v.x -= l; v.y -= l; v.z -= l; v.w -= l;
    *p = v;
}

extern "C" void kernel_launch(void* const* d_in, const int* in_sizes, int n_in,
                              void* d_out, int out_size, void* d_ws, size_t ws_size,
                              hipStream_t stream) {
    const int*   inputs  = (const int*)d_in[0];
    const float* context = (const float*)d_in[1];
    const float* enc     = (const float*)d_in[3];
    const float* emb     = (const float*)d_in[4];
    const float* Wih     = (const float*)d_in[5];
    const float* Whh     = (const float*)d_in[6];
    const float* bih     = (const float*)d_in[7];
    const float* bhh     = (const float*)d_in[8];
    const float* linW    = (const float*)d_in[9];
    const float* linb    = (const float*)d_in[10];
    const float* attnW   = (const float*)d_in[11];
    const float* attnb   = (const float*)d_in[12];
    float* out = (float*)d_out;

    char* w = (char*)d_ws;
    unsigned short* Ghi = (unsigned short*)w; w += (size_t)1536 * KGRU * 2;
    unsigned short* Glo = (unsigned short*)w; w += (size_t)1536 * KGRU * 2;
    float* energies = (float*)w;              w += (size_t)B * T * 512 * 4;
    float* h_t      = (float*)w;              w += (size_t)H * B * 4;
    unsigned short* Xghi[2]; unsigned short* Xglo[2];
    unsigned char* X8[2]; float* Xf[2];
    for (int q = 0; q < 2; ++q) {
        Xghi[q] = (unsigned short*)w; w += (size_t)B * KGRU * 2;
        Xglo[q] = (unsigned short*)w; w += (size_t)B * KGRU * 2;
        Xf[q]   = (float*)w;          w += (size_t)B * KLIN * 4;
        X8[q]   = (unsigned char*)w;  w += (size_t)B * KLIN;
    }
    float* Pm  = (float*)w; w += (size_t)32 * 500 * 4;
    int*   Pa  = (int*)w;   w += (size_t)32 * 500 * 4;
    float* Pm2 = (float*)w; w += (size_t)32 * 500 * 4;
    int*   Pa2 = (int*)w;   w += (size_t)32 * 500 * 4;
    float* Ps  = (float*)w; w += (size_t)32 * 500 * 4;
    float* lse_buf = (float*)w; w += (size_t)B * L * 4;
    unsigned char* W8 = (unsigned char*)w; w += (size_t)V * KLIN;   // 32.8 MB

    presplit_lin8<<<16000, 256, 0, stream>>>(linW, W8);
    presplit_gru<<<1152, 256, 0, stream>>>(Wih, Whh, Ghi, Glo);
    init_state<<<64, 256, 0, stream>>>(inputs, context, emb, h_t, Xghi[0], Xglo[0], X8[0], Xf[0]);
    energies_gemm<<<dim3(128, 8), 256, 0, stream>>>(enc, attnW, attnb, energies);

    for (int t = 0; t < L; ++t) {
        int r = t & 1, n = (t + 1) & 1;
        gru_fused<<<32, 384, 0, stream>>>(Ghi, Glo, Xghi[r], Xglo[r],
                                          Xghi[n], Xglo[n], X8[r], Xf[r],
                                          bih, bhh, h_t);
        score_attn<<<532, 256, 0, stream>>>(W8, linb, X8[r],
                                            X8[n], Xf[n], Xghi[n], Xglo[n],
                                            h_t, energies, enc, out,
                                            Pm, Pa, Pm2, Pa2, Ps, t);
        finalize<<<32, 256, 0, stream>>>(Pm, Pa, Pm2, Pa2, Ps, linW, linb,
                                         Xf[r], emb, Xghi[n], Xglo[n], lse_buf, t);
    }
    subtract_lse<<<48000, 256, 0, stream>>>(out, lse_buf);
}